// Round 2
// baseline (91224.780 us; speedup 1.0000x reference)
//
#include <hip/hip_runtime.h>
#include <hip/hip_cooperative_groups.h>
#include <cstddef>

namespace cg = cooperative_groups;

#define Vv 32000
#define Ee 1024
#define Hh 1024
#define Bb 64
#define Ss 128
#define Tt 32
#define H3 3072
#define KSPLIT 8
#define CH 16
#define ENC_GRID 384     // = 48 ntiles * 8 ksplits (gh phase, 1 task/block)
#define DEC_GRID 512     // 2 blocks/CU; fc phase = 500 tasks

// ===========================================================================
// Shared device helpers (identical arithmetic to the legacy kernels)
// ===========================================================================
__device__ __forceinline__
void mm_tile(const float* __restrict__ arow, const float* __restrict__ wrow,
             float (&As)[16][64], float (&Bs)[16][64], float (&acc)[4][4],
             int kbeg, int kend)
{
  const int tid = threadIdx.x;
  const int lk = (tid & 3) << 2;
  const int lm = tid >> 2;
  const int tm = (tid >> 4) << 2;
  const int tn = (tid & 15) << 2;
  #pragma unroll
  for (int i = 0; i < 4; ++i)
    #pragma unroll
    for (int j = 0; j < 4; ++j) acc[i][j] = 0.f;

  for (int k0 = kbeg; k0 < kend; k0 += 16) {
    float4 a = *(const float4*)(arow + k0 + lk);
    As[lk+0][lm] = a.x; As[lk+1][lm] = a.y;
    As[lk+2][lm] = a.z; As[lk+3][lm] = a.w;
    float4 w = *(const float4*)(wrow + k0 + lk);
    Bs[lk+0][lm] = w.x; Bs[lk+1][lm] = w.y;
    Bs[lk+2][lm] = w.z; Bs[lk+3][lm] = w.w;
    __syncthreads();
    #pragma unroll
    for (int kk = 0; kk < 16; ++kk) {
      const float4 av = *(const float4*)&As[kk][tm];
      const float4 bv = *(const float4*)&Bs[kk][tn];
      acc[0][0] += av.x*bv.x; acc[0][1] += av.x*bv.y; acc[0][2] += av.x*bv.z; acc[0][3] += av.x*bv.w;
      acc[1][0] += av.y*bv.x; acc[1][1] += av.y*bv.y; acc[1][2] += av.y*bv.z; acc[1][3] += av.y*bv.w;
      acc[2][0] += av.z*bv.x; acc[2][1] += av.z*bv.y; acc[2][2] += av.z*bv.z; acc[2][3] += av.z*bv.w;
      acc[3][0] += av.w*bv.x; acc[3][1] += av.w*bv.y; acc[3][2] += av.w*bv.z; acc[3][3] += av.w*bv.w;
    }
    __syncthreads();
  }
}

__device__ __forceinline__
void store_tile(float* __restrict__ dst, const float (&acc)[4][4])
{
  const int tid = threadIdx.x;
  const int tm = (tid >> 4) << 2;
  const int tn = (tid & 15) << 2;
  #pragma unroll
  for (int i = 0; i < 4; ++i) {
    float4 v; v.x = acc[i][0]; v.y = acc[i][1]; v.z = acc[i][2]; v.w = acc[i][3];
    *(float4*)(dst + (size_t)(tm + i) * H3 + tn) = v;
  }
}

__device__ __forceinline__
void gates_op(int idx, const float* __restrict__ gi, int ngi,
              const float* __restrict__ gh, int ngh,
              const float* __restrict__ bih, const float* __restrict__ bhh,
              float* __restrict__ h, float* __restrict__ hsave,
              const int* __restrict__ src_len, int t, int use_mask)
{
  int b = idx >> 10, j = idx & 1023;
  float sir = 0.f, siz = 0.f, sin_ = 0.f;
  for (int p = 0; p < ngi; ++p) {
    const float* g = gi + (size_t)p * (64 * H3) + (size_t)b * H3 + j;
    sir += g[0]; siz += g[1024]; sin_ += g[2048];
  }
  float shr = 0.f, shz = 0.f, shn = 0.f;
  for (int p = 0; p < ngh; ++p) {
    const float* g = gh + (size_t)p * (64 * H3) + (size_t)b * H3 + j;
    shr += g[0]; shz += g[1024]; shn += g[2048];
  }
  float r = 1.f / (1.f + expf(-(sir + bih[j]        + shr + bhh[j])));
  float z = 1.f / (1.f + expf(-(siz + bih[j + 1024] + shz + bhh[j + 1024])));
  float n = tanhf(sin_ + bih[j + 2048] + r * (shn + bhh[j + 2048]));
  float hp = h[idx];
  float hn = (1.f - z) * n + z * hp;
  if (use_mask && t >= src_len[b]) hn = hp;
  h[idx] = hn;
  if (hsave) hsave[idx] = hn;
}

// Grid-wide barrier hardened with explicit agent-scope fences (per-XCD L2
// non-coherence insurance; __threadfence == agent seq_cst fence on gfx950).
__device__ __forceinline__ void gsync(cg::grid_group& g)
{
  __threadfence();
  g.sync();
  __threadfence();
}

// ===========================================================================
// Persistent encoder layer (cooperative)
// ===========================================================================
template<bool GATHER>
__global__ __launch_bounds__(256, 2)
void enc_layer(const float* __restrict__ emb, const int* __restrict__ src,
               const float* __restrict__ hall_in,
               const float* __restrict__ Wih, const float* __restrict__ Whh,
               const float* __restrict__ bih, const float* __restrict__ bhh,
               float* __restrict__ h, float* __restrict__ hsave,
               float* __restrict__ gi_ch, float* __restrict__ parts,
               const int* __restrict__ src_len)
{
  cg::grid_group grid = cg::this_grid();
  __shared__ __align__(16) float As[16][64];
  __shared__ __align__(16) float Bs[16][64];
  const int tid = threadIdx.x;
  const int lm = tid >> 2;

  for (int c = 0; c < Ss; c += CH) {
    // ---- phase A: gi for CH timesteps ----
    for (int task = blockIdx.x; task < CH * 48; task += gridDim.x) {
      const int tloc = task / 48;
      const int ntile = task - tloc * 48;
      const float* arow;
      if (GATHER) {
        int m = (c + tloc) * 64 + lm;      // m = t*64 + b
        int b = m & 63, t = m >> 6;
        arow = emb + (size_t)src[b * Ss + t] * Ee;
      } else {
        arow = hall_in + (size_t)((c + tloc) * 64 + lm) * 1024;
      }
      const float* wrow = Wih + (size_t)(ntile * 64 + lm) * 1024;
      float acc[4][4];
      mm_tile(arow, wrow, As, Bs, acc, 0, 1024);
      store_tile(gi_ch + (size_t)(tloc * 64) * H3 + ntile * 64, acc);
    }
    gsync(grid);

    // ---- phase B: CH sequential GRU steps ----
    for (int t = c; t < c + CH; ++t) {
      if (blockIdx.x < 48 * KSPLIT) {
        const int ntile = blockIdx.x % 48;
        const int ks = blockIdx.x / 48;
        const float* arow = h + (size_t)lm * 1024;
        const float* wrow = Whh + (size_t)(ntile * 64 + lm) * 1024;
        float acc[4][4];
        mm_tile(arow, wrow, As, Bs, acc, ks * 128, ks * 128 + 128);
        store_tile(parts + (size_t)ks * (64 * H3) + ntile * 64, acc);
      }
      gsync(grid);
      const int idx = blockIdx.x * 256 + tid;
      if (idx < Bb * Hh) {
        float* hs_t = hsave ? hsave + (size_t)t * (Bb * Hh) : nullptr;
        gates_op(idx, gi_ch + (size_t)(t - c) * (64 * H3), 1,
                 parts, KSPLIT, bih, bhh, h, hs_t, src_len, t, 1);
      }
      gsync(grid);
    }
  }
}

// ===========================================================================
// Persistent decoder (cooperative)
// ===========================================================================
__global__ __launch_bounds__(256, 2)
void dec_all(const float* __restrict__ emb,
             const float* __restrict__ Wih0, const float* __restrict__ Whh0,
             const float* __restrict__ bih0, const float* __restrict__ bhh0,
             const float* __restrict__ Wih1, const float* __restrict__ Whh1,
             const float* __restrict__ bih1, const float* __restrict__ bhh1,
             const float* __restrict__ fcW, const float* __restrict__ fcb,
             float* __restrict__ h0, float* __restrict__ h1,
             float* __restrict__ parts0, float* __restrict__ parts1,
             int* __restrict__ tok, float* __restrict__ outp)
{
  cg::grid_group grid = cg::this_grid();
  __shared__ __align__(16) float As[16][64];
  __shared__ __align__(16) float Bs[16][64];
  __shared__ float sv[256];
  __shared__ int   si[256];
  const int tid = threadIdx.x;
  const int lm = tid >> 2;
  const int tm = (tid >> 4) << 2;
  const int tn = (tid & 15) << 2;

  for (int t = 1; t < Tt; ++t) {
    // ---- layer 0: gi (gather emb[tok]) + gh, split-K, dual slot ----
    for (int task = blockIdx.x; task < 2 * 48 * KSPLIT; task += gridDim.x) {
      const int slot = task / (48 * KSPLIT);
      const int r = task - slot * (48 * KSPLIT);
      const int ntile = r % 48;
      const int ks = r / 48;
      const float* arow = (slot == 0) ? emb + (size_t)tok[lm] * Ee
                                      : h0 + (size_t)lm * 1024;
      const float* wrow = ((slot == 0) ? Wih0 : Whh0) + (size_t)(ntile * 64 + lm) * 1024;
      float acc[4][4];
      mm_tile(arow, wrow, As, Bs, acc, ks * 128, ks * 128 + 128);
      store_tile(((slot == 0) ? parts0 : parts1) + (size_t)ks * (64 * H3) + ntile * 64, acc);
    }
    gsync(grid);
    {
      const int idx = blockIdx.x * 256 + tid;
      if (idx < Bb * Hh)
        gates_op(idx, parts0, KSPLIT, parts1, KSPLIT, bih0, bhh0, h0,
                 nullptr, nullptr, 0, 0);
    }
    gsync(grid);

    // ---- layer 1: gi (from h0) + gh (from h1), dual slot ----
    for (int task = blockIdx.x; task < 2 * 48 * KSPLIT; task += gridDim.x) {
      const int slot = task / (48 * KSPLIT);
      const int r = task - slot * (48 * KSPLIT);
      const int ntile = r % 48;
      const int ks = r / 48;
      const float* arow = (slot == 0) ? h0 + (size_t)lm * 1024
                                      : h1 + (size_t)lm * 1024;
      const float* wrow = ((slot == 0) ? Wih1 : Whh1) + (size_t)(ntile * 64 + lm) * 1024;
      float acc[4][4];
      mm_tile(arow, wrow, As, Bs, acc, ks * 128, ks * 128 + 128);
      store_tile(((slot == 0) ? parts0 : parts1) + (size_t)ks * (64 * H3) + ntile * 64, acc);
    }
    gsync(grid);
    {
      const int idx = blockIdx.x * 256 + tid;
      if (idx < Bb * Hh)
        gates_op(idx, parts0, KSPLIT, parts1, KSPLIT, bih1, bhh1, h1,
                 nullptr, nullptr, 0, 0);
    }
    gsync(grid);

    // ---- fc: 500 tasks of 64x64, full K ----
    for (int task = blockIdx.x; task < Vv / 64; task += gridDim.x) {
      const int n0 = task * 64;
      const float* arow = h1 + (size_t)lm * 1024;
      const float* wrow = fcW + (size_t)(n0 + lm) * 1024;
      float acc[4][4];
      mm_tile(arow, wrow, As, Bs, acc, 0, 1024);
      #pragma unroll
      for (int i = 0; i < 4; ++i) {
        float4 v;
        v.x = acc[i][0] + fcb[n0 + tn + 0];
        v.y = acc[i][1] + fcb[n0 + tn + 1];
        v.z = acc[i][2] + fcb[n0 + tn + 2];
        v.w = acc[i][3] + fcb[n0 + tn + 3];
        *(float4*)(outp + (size_t)(tm + i) * Tt * Vv + (size_t)t * Vv + n0 + tn) = v;
      }
    }
    gsync(grid);

    // ---- argmax per batch row ----
    if (blockIdx.x < Bb) {
      const int b = blockIdx.x;
      const float* logits = outp + (size_t)b * Tt * Vv + (size_t)t * Vv;
      float best = -3.4e38f; int bi = 0;
      for (int j = tid; j < Vv; j += 256) {
        float v = logits[j];
        if (v > best) { best = v; bi = j; }
      }
      sv[tid] = best; si[tid] = bi;
      __syncthreads();
      for (int s = 128; s > 0; s >>= 1) {
        if (tid < s) {
          if (sv[tid + s] > sv[tid] || (sv[tid + s] == sv[tid] && si[tid + s] < si[tid])) {
            sv[tid] = sv[tid + s]; si[tid] = si[tid + s];
          }
        }
        __syncthreads();
      }
      if (tid == 0) tok[b] = si[0];
    }
    gsync(grid);
  }
}

// ===========================================================================
// Legacy kernels (verbatim from the passing version) — fallback path
// ===========================================================================
template<bool GATHER>
__global__ __launch_bounds__(256)
void big_gemm(const float* __restrict__ Af,
              const float* __restrict__ emb,
              const int* __restrict__ src,
              const float* __restrict__ W,
              float* __restrict__ C, int m_off)
{
  __shared__ __align__(16) float As[16][64];
  __shared__ __align__(16) float Bs[16][64];
  const int tid = threadIdx.x;
  const int m0 = blockIdx.x * 64;
  const int n0 = blockIdx.y * 64;
  const int lm = tid >> 2;

  const float* arow;
  if (GATHER) {
    int m = m_off + m0 + lm;
    int b = m & (Bb - 1), t = m >> 6;
    arow = emb + (size_t)src[b * Ss + t] * Ee;
  } else {
    arow = Af + (size_t)(m_off + m0 + lm) * 1024;
  }
  const float* wrow = W + (size_t)(n0 + lm) * 1024;
  float acc[4][4];
  mm_tile(arow, wrow, As, Bs, acc, 0, 1024);
  store_tile(C + (size_t)m0 * H3 + n0, acc);
}

template<bool S0_GATHER>
__global__ __launch_bounds__(256)
void small_gemm(const float* __restrict__ A0, const float* __restrict__ gemb,
                const int* __restrict__ rows0,
                const float* __restrict__ W0, float* __restrict__ P0,
                const float* __restrict__ A1, const float* __restrict__ W1,
                float* __restrict__ P1)
{
  __shared__ __align__(16) float As[16][64];
  __shared__ __align__(16) float Bs[16][64];
  const int tid = threadIdx.x;
  const int n0 = blockIdx.x * 64;
  const int kbase = blockIdx.y * 128;
  const int slot = blockIdx.z;
  const float* W = (slot == 0) ? W0 : W1;
  float* dst = ((slot == 0) ? P0 : P1) + (size_t)blockIdx.y * (64 * H3);
  const int lm = tid >> 2;

  const float* arow;
  if (S0_GATHER && (slot == 0)) {
    arow = gemb + (size_t)rows0[lm] * Ee;
  } else {
    const float* Af = (slot == 0) ? A0 : A1;
    arow = Af + (size_t)lm * 1024;
  }
  const float* wrow = W + (size_t)(n0 + lm) * 1024;
  float acc[4][4];
  mm_tile(arow, wrow, As, Bs, acc, kbase, kbase + 128);
  store_tile(dst + n0, acc);
}

__global__ __launch_bounds__(256)
void gru_gates(const float* __restrict__ gi, int ngi,
               const float* __restrict__ gh, int ngh,
               const float* __restrict__ bih, const float* __restrict__ bhh,
               float* __restrict__ h, float* __restrict__ hsave,
               const int* __restrict__ src_len, int t, int use_mask)
{
  int idx = blockIdx.x * 256 + threadIdx.x;
  gates_op(idx, gi, ngi, gh, ngh, bih, bhh, h, hsave, src_len, t, use_mask);
}

__global__ __launch_bounds__(256)
void fc_gemm(const float* __restrict__ A, const float* __restrict__ W,
             const float* __restrict__ bias,
             float* __restrict__ out, int t)
{
  __shared__ __align__(16) float As[16][64];
  __shared__ __align__(16) float Bs[16][64];
  const int tid = threadIdx.x;
  const int n0 = blockIdx.x * 64;
  const int lm = tid >> 2;
  const float* arow = A + (size_t)lm * 1024;
  const float* wrow = W + (size_t)(n0 + lm) * 1024;
  float acc[4][4];
  mm_tile(arow, wrow, As, Bs, acc, 0, 1024);
  const int tm = (tid >> 4) << 2;
  const int tn = (tid & 15) << 2;
  #pragma unroll
  for (int i = 0; i < 4; ++i) {
    int m = tm + i;
    float4 v;
    v.x = acc[i][0] + bias[n0 + tn + 0];
    v.y = acc[i][1] + bias[n0 + tn + 1];
    v.z = acc[i][2] + bias[n0 + tn + 2];
    v.w = acc[i][3] + bias[n0 + tn + 3];
    *(float4*)(out + (size_t)m * Tt * Vv + (size_t)t * Vv + n0 + tn) = v;
  }
}

__global__ __launch_bounds__(256)
void argmax_k(const float* __restrict__ out, int t, int* __restrict__ tok)
{
  __shared__ float sv[256];
  __shared__ int   si[256];
  const int b = blockIdx.x;
  const int tid = threadIdx.x;
  const float* logits = out + (size_t)b * Tt * Vv + (size_t)t * Vv;
  float best = -3.4e38f; int bi = 0;
  for (int j = tid; j < Vv; j += 256) {
    float v = logits[j];
    if (v > best) { best = v; bi = j; }
  }
  sv[tid] = best; si[tid] = bi;
  __syncthreads();
  for (int s = 128; s > 0; s >>= 1) {
    if (tid < s) {
      if (sv[tid + s] > sv[tid] || (sv[tid + s] == sv[tid] && si[tid + s] < si[tid])) {
        sv[tid] = sv[tid + s]; si[tid] = si[tid + s];
      }
    }
    __syncthreads();
  }
  if (tid == 0) tok[b] = si[0];
}

__global__ void zero_f32(float* __restrict__ p, int n)
{
  int i = blockIdx.x * 256 + threadIdx.x;
  if (i < n) p[i] = 0.f;
}

__global__ void zero_first(float* __restrict__ out)
{
  int i = blockIdx.x * 256 + threadIdx.x;
  if (i < Bb * Vv) {
    int b = i / Vv, v = i - b * Vv;
    out[(size_t)b * Tt * Vv + v] = 0.f;
  }
}

__global__ void tok_init(int* __restrict__ tok, const int* __restrict__ trg)
{
  int i = threadIdx.x;
  if (i < Bb) tok[i] = trg[i * Tt];
}

// ===========================================================================

extern "C" void kernel_launch(void* const* d_in, const int* in_sizes, int n_in,
                              void* d_out, int out_size, void* d_ws, size_t ws_size,
                              hipStream_t stream)
{
  const int*   src     = (const int*)d_in[0];
  const int*   src_len = (const int*)d_in[1];
  const int*   trg     = (const int*)d_in[2];
  const float* emb     = (const float*)d_in[3];
  const float* enc_Wih = (const float*)d_in[4];
  const float* enc_Whh = (const float*)d_in[5];
  const float* enc_bih = (const float*)d_in[6];
  const float* enc_bhh = (const float*)d_in[7];
  const float* dec_Wih = (const float*)d_in[8];
  const float* dec_Whh = (const float*)d_in[9];
  const float* dec_bih = (const float*)d_in[10];
  const float* dec_bhh = (const float*)d_in[11];
  const float* fc_W    = (const float*)d_in[12];
  const float* fc_b    = (const float*)d_in[13];
  float* outp = (float*)d_out;

  float* ws = (float*)d_ws;
  float* parts0  = ws;
  float* parts1  = parts0 + (size_t)KSPLIT * Bb * H3;
  float* h_state = parts1 + (size_t)KSPLIT * Bb * H3;
  int*   tok     = (int*)(h_state + 2 * Bb * Hh);
  float* gi_ch   = (float*)(tok + 64);
  float* h_all   = gi_ch + (size_t)CH * Bb * H3;

  const size_t Wl = (size_t)H3 * Hh;
  float* h0 = h_state;
  float* h1 = h_state + Bb * Hh;

  // ---- inits ----
  zero_f32<<<(2 * Bb * Hh + 255) / 256, 256, 0, stream>>>(h_state, 2 * Bb * Hh);
  zero_first<<<(Bb * Vv + 255) / 256, 256, 0, stream>>>(outp);
  tok_init<<<1, 64, 0, stream>>>(tok, trg);

  // ---- cooperative fast path (error-checked) ----
  bool coop_ok = true;
  {
    const float* hall_in = h_all;
    const float* Wih = enc_Wih;
    const float* Whh = enc_Whh;
    const float* bi  = enc_bih;
    const float* bh  = enc_bhh;
    float* hcur = h0;
    float* hs   = h_all;
    void* args[] = { (void*)&emb, (void*)&src, (void*)&hall_in,
                     (void*)&Wih, (void*)&Whh, (void*)&bi, (void*)&bh,
                     (void*)&hcur, (void*)&hs, (void*)&gi_ch, (void*)&parts1,
                     (void*)&src_len };
    coop_ok = (hipLaunchCooperativeKernel(
                   reinterpret_cast<const void*>(&enc_layer<true>),
                   dim3(ENC_GRID), dim3(256), args, 0, stream) == hipSuccess);
  }
  if (coop_ok) {
    const float* hall_in = h_all;
    const float* Wih = enc_Wih + Wl;
    const float* Whh = enc_Whh + Wl;
    const float* bi  = enc_bih + H3;
    const float* bh  = enc_bhh + H3;
    float* hcur = h1;
    float* hs   = nullptr;
    void* args[] = { (void*)&emb, (void*)&src, (void*)&hall_in,
                     (void*)&Wih, (void*)&Whh, (void*)&bi, (void*)&bh,
                     (void*)&hcur, (void*)&hs, (void*)&gi_ch, (void*)&parts1,
                     (void*)&src_len };
    coop_ok = (hipLaunchCooperativeKernel(
                   reinterpret_cast<const void*>(&enc_layer<false>),
                   dim3(ENC_GRID), dim3(256), args, 0, stream) == hipSuccess);
  }
  if (coop_ok) {
    const float* Wih0 = dec_Wih;       const float* Whh0 = dec_Whh;
    const float* bi0  = dec_bih;       const float* bh0  = dec_bhh;
    const float* Wih1 = dec_Wih + Wl;  const float* Whh1 = dec_Whh + Wl;
    const float* bi1  = dec_bih + H3;  const float* bh1  = dec_bhh + H3;
    void* args[] = { (void*)&emb,
                     (void*)&Wih0, (void*)&Whh0, (void*)&bi0, (void*)&bh0,
                     (void*)&Wih1, (void*)&Whh1, (void*)&bi1, (void*)&bh1,
                     (void*)&fc_W, (void*)&fc_b,
                     (void*)&h0, (void*)&h1, (void*)&parts0, (void*)&parts1,
                     (void*)&tok, (void*)&outp };
    coop_ok = (hipLaunchCooperativeKernel(
                   reinterpret_cast<const void*>(&dec_all),
                   dim3(DEC_GRID), dim3(256), args, 0, stream) == hipSuccess);
  }

  if (!coop_ok) {
    // ---- legacy fallback: full schedule from scratch (fresh state) ----
    zero_f32<<<(2 * Bb * Hh + 255) / 256, 256, 0, stream>>>(h_state, 2 * Bb * Hh);
    zero_first<<<(Bb * Vv + 255) / 256, 256, 0, stream>>>(outp);
    tok_init<<<1, 64, 0, stream>>>(tok, trg);

    // encoder layer 0
    for (int c = 0; c < Ss; c += CH) {
      big_gemm<true><<<dim3(CH, 48), 256, 0, stream>>>(nullptr, emb, src, enc_Wih,
                                                       gi_ch, c * Bb);
      for (int t = c; t < c + CH; ++t) {
        small_gemm<false><<<dim3(48, KSPLIT, 1), 256, 0, stream>>>(
            h0, nullptr, nullptr, enc_Whh, parts1, nullptr, nullptr, nullptr);
        gru_gates<<<256, 256, 0, stream>>>(gi_ch + (size_t)(t - c) * Bb * H3, 1,
                                           parts1, KSPLIT, enc_bih, enc_bhh, h0,
                                           h_all + (size_t)t * Bb * Hh, src_len, t, 1);
      }
    }
    // encoder layer 1
    for (int c = 0; c < Ss; c += CH) {
      big_gemm<false><<<dim3(CH, 48), 256, 0, stream>>>(h_all, nullptr, nullptr,
                                                        enc_Wih + Wl, gi_ch, c * Bb);
      for (int t = c; t < c + CH; ++t) {
        small_gemm<false><<<dim3(48, KSPLIT, 1), 256, 0, stream>>>(
            h1, nullptr, nullptr, enc_Whh + Wl, parts1, nullptr, nullptr, nullptr);
        gru_gates<<<256, 256, 0, stream>>>(gi_ch + (size_t)(t - c) * Bb * H3, 1,
                                           parts1, KSPLIT, enc_bih + H3, enc_bhh + H3, h1,
                                           nullptr, src_len, t, 1);
      }
    }
    // decoder
    for (int t = 1; t < Tt; ++t) {
      small_gemm<true><<<dim3(48, KSPLIT, 2), 256, 0, stream>>>(
          nullptr, emb, tok, dec_Wih, parts0, h0, dec_Whh, parts1);
      gru_gates<<<256, 256, 0, stream>>>(parts0, KSPLIT, parts1, KSPLIT,
                                         dec_bih, dec_bhh, h0, nullptr, nullptr, 0, 0);
      small_gemm<false><<<dim3(48, KSPLIT, 2), 256, 0, stream>>>(
          h0, nullptr, nullptr, dec_Wih + Wl, parts0, h1, dec_Whh + Wl, parts1);
      gru_gates<<<256, 256, 0, stream>>>(parts0, KSPLIT, parts1, KSPLIT,
                                         dec_bih + H3, dec_bhh + H3, h1, nullptr, nullptr, 0, 0);
      fc_gemm<<<dim3(Vv / 64), 256, 0, stream>>>(h1, fc_W, fc_b, outp, t);
      argmax_k<<<64, 256, 0, stream>>>(outp, t, tok);
    }
  }
}

// Round 4
// 9899.654 us; speedup vs baseline: 9.2149x; 9.2149x over previous
//
#include <hip/hip_runtime.h>
#include <cstddef>

#define Vv 32000
#define Ee 1024
#define Hh 1024
#define Bb 64
#define Ss 128
#define Tt 32
#define H3 3072
#define KSPLIT 8
#define CH 16

// ===========================================================================
// Shared device helpers (identical arithmetic to the proven kernels)
// ===========================================================================
__device__ __forceinline__
void mm_tile(const float* __restrict__ arow, const float* __restrict__ wrow,
             float (&As)[16][64], float (&Bs)[16][64], float (&acc)[4][4],
             int kbeg, int kend)
{
  const int tid = threadIdx.x;
  const int lk = (tid & 3) << 2;
  const int lm = tid >> 2;
  const int tm = (tid >> 4) << 2;
  const int tn = (tid & 15) << 2;
  #pragma unroll
  for (int i = 0; i < 4; ++i)
    #pragma unroll
    for (int j = 0; j < 4; ++j) acc[i][j] = 0.f;

  for (int k0 = kbeg; k0 < kend; k0 += 16) {
    float4 a = *(const float4*)(arow + k0 + lk);
    As[lk+0][lm] = a.x; As[lk+1][lm] = a.y;
    As[lk+2][lm] = a.z; As[lk+3][lm] = a.w;
    float4 w = *(const float4*)(wrow + k0 + lk);
    Bs[lk+0][lm] = w.x; Bs[lk+1][lm] = w.y;
    Bs[lk+2][lm] = w.z; Bs[lk+3][lm] = w.w;
    __syncthreads();
    #pragma unroll
    for (int kk = 0; kk < 16; ++kk) {
      const float4 av = *(const float4*)&As[kk][tm];
      const float4 bv = *(const float4*)&Bs[kk][tn];
      acc[0][0] += av.x*bv.x; acc[0][1] += av.x*bv.y; acc[0][2] += av.x*bv.z; acc[0][3] += av.x*bv.w;
      acc[1][0] += av.y*bv.x; acc[1][1] += av.y*bv.y; acc[1][2] += av.y*bv.z; acc[1][3] += av.y*bv.w;
      acc[2][0] += av.z*bv.x; acc[2][1] += av.z*bv.y; acc[2][2] += av.z*bv.z; acc[2][3] += av.z*bv.w;
      acc[3][0] += av.w*bv.x; acc[3][1] += av.w*bv.y; acc[3][2] += av.w*bv.z; acc[3][3] += av.w*bv.w;
    }
    __syncthreads();
  }
}

__device__ __forceinline__
void store_tile(float* __restrict__ dst, const float (&acc)[4][4])
{
  const int tid = threadIdx.x;
  const int tm = (tid >> 4) << 2;
  const int tn = (tid & 15) << 2;
  #pragma unroll
  for (int i = 0; i < 4; ++i) {
    float4 v; v.x = acc[i][0]; v.y = acc[i][1]; v.z = acc[i][2]; v.w = acc[i][3];
    *(float4*)(dst + (size_t)(tm + i) * H3 + tn) = v;
  }
}

__device__ __forceinline__
void gates_op(int idx, const float* __restrict__ gi, int ngi,
              const float* __restrict__ gh, int ngh,
              const float* __restrict__ bih, const float* __restrict__ bhh,
              float* __restrict__ h, float* __restrict__ hsave,
              const int* __restrict__ src_len, int t, int use_mask)
{
  int b = idx >> 10, j = idx & 1023;
  float sir = 0.f, siz = 0.f, sin_ = 0.f;
  for (int p = 0; p < ngi; ++p) {
    const float* g = gi + (size_t)p * (64 * H3) + (size_t)b * H3 + j;
    sir += g[0]; siz += g[1024]; sin_ += g[2048];
  }
  float shr = 0.f, shz = 0.f, shn = 0.f;
  for (int p = 0; p < ngh; ++p) {
    const float* g = gh + (size_t)p * (64 * H3) + (size_t)b * H3 + j;
    shr += g[0]; shz += g[1024]; shn += g[2048];
  }
  float r = 1.f / (1.f + expf(-(sir + bih[j]        + shr + bhh[j])));
  float z = 1.f / (1.f + expf(-(siz + bih[j + 1024] + shz + bhh[j + 1024])));
  float n = tanhf(sin_ + bih[j + 2048] + r * (shn + bhh[j + 2048]));
  float hp = h[idx];
  float hn = (1.f - z) * n + z * hp;
  if (use_mask && t >= src_len[b]) hn = hp;
  h[idx] = hn;
  if (hsave) hsave[idx] = hn;
}

// ===========================================================================
// Chunked gi GEMM for encoder layer 0 (gathers emb[src]).
// ===========================================================================
__global__ __launch_bounds__(256)
void big_gemm_gather(const float* __restrict__ emb,
                     const int* __restrict__ src,
                     const float* __restrict__ W,
                     float* __restrict__ C, int m_off)
{
  __shared__ __align__(16) float As[16][64];
  __shared__ __align__(16) float Bs[16][64];
  const int tid = threadIdx.x;
  const int m0 = blockIdx.x * 64;
  const int n0 = blockIdx.y * 64;
  const int lm = tid >> 2;

  int m = m_off + m0 + lm;                 // global row: t*64 + b
  int b = m & (Bb - 1), t = m >> 6;
  const float* arow = emb + (size_t)src[b * Ss + t] * Ee;
  const float* wrow = W + (size_t)(n0 + lm) * 1024;
  float acc[4][4];
  mm_tile(arow, wrow, As, Bs, acc, 0, 1024);
  store_tile(C + (size_t)m0 * H3 + n0, acc);
}

// ===========================================================================
// Pipelined encoder macro-step GEMM: gh0(t) || gi1(t-1) || gh1(t-1).
// Each sub-GEMM = 48 ntiles x 8 ksplits = 384 blocks of 64x64x128.
// ===========================================================================
__global__ __launch_bounds__(256)
void fat_enc(const float* __restrict__ h0, const float* __restrict__ h1,
             const float* __restrict__ Whh0, const float* __restrict__ Wih1,
             const float* __restrict__ Whh1,
             float* __restrict__ pgh0, float* __restrict__ pgi1,
             float* __restrict__ pgh1, int has0)
{
  __shared__ __align__(16) float As[16][64];
  __shared__ __align__(16) float Bs[16][64];
  const int lm = threadIdx.x >> 2;
  int r = blockIdx.x;

  if (has0 && r < 384) {
    const int ntile = r % 48;
    const int ks = r / 48;
    const float* arow = h0 + (size_t)lm * 1024;
    const float* wrow = Whh0 + (size_t)(ntile * 64 + lm) * 1024;
    float acc[4][4];
    mm_tile(arow, wrow, As, Bs, acc, ks * 128, ks * 128 + 128);
    store_tile(pgh0 + (size_t)ks * (64 * H3) + ntile * 64, acc);
    return;
  }
  r -= has0 ? 384 : 0;
  const int which = r / 384;               // 0 = gi1, 1 = gh1
  const int rr = r - which * 384;
  const int ntile = rr % 48;
  const int ks = rr / 48;
  const float* arow = (which == 0 ? h0 : h1) + (size_t)lm * 1024;
  const float* wrow = (which == 0 ? Wih1 : Whh1) + (size_t)(ntile * 64 + lm) * 1024;
  float acc[4][4];
  mm_tile(arow, wrow, As, Bs, acc, ks * 128, ks * 128 + 128);
  store_tile((which == 0 ? pgi1 : pgh1) + (size_t)ks * (64 * H3) + ntile * 64, acc);
}

// ===========================================================================
// Dual gates: layer0 gates(t) on blocks [0,256); layer1 gates(t-1) on [256,512).
// ===========================================================================
__global__ __launch_bounds__(256)
void gates2(const float* __restrict__ gi0, const float* __restrict__ pgh0,
            const float* __restrict__ bih0, const float* __restrict__ bhh0,
            float* __restrict__ h0,
            const float* __restrict__ pgi1, const float* __restrict__ pgh1,
            const float* __restrict__ bih1, const float* __restrict__ bhh1,
            float* __restrict__ h1,
            const int* __restrict__ src_len, int t, int has0, int has1)
{
  const int blk = blockIdx.x;
  if (blk < 256) {
    if (!has0) return;
    const int idx = blk * 256 + threadIdx.x;
    gates_op(idx, gi0, 1, pgh0, KSPLIT, bih0, bhh0, h0, nullptr, src_len, t, 1);
  } else {
    if (!has1) return;
    const int idx = (blk - 256) * 256 + threadIdx.x;
    gates_op(idx, pgi1, KSPLIT, pgh1, KSPLIT, bih1, bhh1, h1, nullptr, src_len, t - 1, 1);
  }
}

// ===========================================================================
// Decoder kernels (verbatim from the proven 11.58 ms version)
// ===========================================================================
template<bool S0_GATHER>
__global__ __launch_bounds__(256)
void small_gemm(const float* __restrict__ A0, const float* __restrict__ gemb,
                const int* __restrict__ rows0,
                const float* __restrict__ W0, float* __restrict__ P0,
                const float* __restrict__ A1, const float* __restrict__ W1,
                float* __restrict__ P1)
{
  __shared__ __align__(16) float As[16][64];
  __shared__ __align__(16) float Bs[16][64];
  const int tid = threadIdx.x;
  const int n0 = blockIdx.x * 64;
  const int kbase = blockIdx.y * 128;
  const int slot = blockIdx.z;
  const float* W = (slot == 0) ? W0 : W1;
  float* dst = ((slot == 0) ? P0 : P1) + (size_t)blockIdx.y * (64 * H3);
  const int lm = tid >> 2;

  const float* arow;
  if (S0_GATHER && (slot == 0)) {
    arow = gemb + (size_t)rows0[lm] * Ee;
  } else {
    const float* Af = (slot == 0) ? A0 : A1;
    arow = Af + (size_t)lm * 1024;
  }
  const float* wrow = W + (size_t)(n0 + lm) * 1024;
  float acc[4][4];
  mm_tile(arow, wrow, As, Bs, acc, kbase, kbase + 128);
  store_tile(dst + n0, acc);
}

__global__ __launch_bounds__(256)
void gru_gates(const float* __restrict__ gi, int ngi,
               const float* __restrict__ gh, int ngh,
               const float* __restrict__ bih, const float* __restrict__ bhh,
               float* __restrict__ h, float* __restrict__ hsave,
               const int* __restrict__ src_len, int t, int use_mask)
{
  int idx = blockIdx.x * 256 + threadIdx.x;
  gates_op(idx, gi, ngi, gh, ngh, bih, bhh, h, hsave, src_len, t, use_mask);
}

__global__ __launch_bounds__(256)
void fc_gemm(const float* __restrict__ A, const float* __restrict__ W,
             const float* __restrict__ bias,
             float* __restrict__ out, int t)
{
  __shared__ __align__(16) float As[16][64];
  __shared__ __align__(16) float Bs[16][64];
  const int tid = threadIdx.x;
  const int n0 = blockIdx.x * 64;
  const int lm = tid >> 2;
  const float* arow = A + (size_t)lm * 1024;
  const float* wrow = W + (size_t)(n0 + lm) * 1024;
  float acc[4][4];
  mm_tile(arow, wrow, As, Bs, acc, 0, 1024);
  const int tm = (tid >> 4) << 2;
  const int tn = (tid & 15) << 2;
  #pragma unroll
  for (int i = 0; i < 4; ++i) {
    int m = tm + i;
    float4 v;
    v.x = acc[i][0] + bias[n0 + tn + 0];
    v.y = acc[i][1] + bias[n0 + tn + 1];
    v.z = acc[i][2] + bias[n0 + tn + 2];
    v.w = acc[i][3] + bias[n0 + tn + 3];
    *(float4*)(out + (size_t)m * Tt * Vv + (size_t)t * Vv + n0 + tn) = v;
  }
}

__global__ __launch_bounds__(256)
void argmax_k(const float* __restrict__ out, int t, int* __restrict__ tok)
{
  __shared__ float sv[256];
  __shared__ int   si[256];
  const int b = blockIdx.x;
  const int tid = threadIdx.x;
  const float* logits = out + (size_t)b * Tt * Vv + (size_t)t * Vv;
  float best = -3.4e38f; int bi = 0;
  for (int j = tid; j < Vv; j += 256) {
    float v = logits[j];
    if (v > best) { best = v; bi = j; }
  }
  sv[tid] = best; si[tid] = bi;
  __syncthreads();
  for (int s = 128; s > 0; s >>= 1) {
    if (tid < s) {
      if (sv[tid + s] > sv[tid] || (sv[tid + s] == sv[tid] && si[tid + s] < si[tid])) {
        sv[tid] = sv[tid + s]; si[tid] = si[tid + s];
      }
    }
    __syncthreads();
  }
  if (tid == 0) tok[b] = si[0];
}

__global__ void zero_f32(float* __restrict__ p, int n)
{
  int i = blockIdx.x * 256 + threadIdx.x;
  if (i < n) p[i] = 0.f;
}

__global__ void zero_first(float* __restrict__ out)
{
  int i = blockIdx.x * 256 + threadIdx.x;
  if (i < Bb * Vv) {
    int b = i / Vv, v = i - b * Vv;
    out[(size_t)b * Tt * Vv + v] = 0.f;
  }
}

__global__ void tok_init(int* __restrict__ tok, const int* __restrict__ trg)
{
  int i = threadIdx.x;
  if (i < Bb) tok[i] = trg[i * Tt];
}

// ===========================================================================

extern "C" void kernel_launch(void* const* d_in, const int* in_sizes, int n_in,
                              void* d_out, int out_size, void* d_ws, size_t ws_size,
                              hipStream_t stream)
{
  const int*   src     = (const int*)d_in[0];
  const int*   src_len = (const int*)d_in[1];
  const int*   trg     = (const int*)d_in[2];
  const float* emb     = (const float*)d_in[3];
  const float* enc_Wih = (const float*)d_in[4];
  const float* enc_Whh = (const float*)d_in[5];
  const float* enc_bih = (const float*)d_in[6];
  const float* enc_bhh = (const float*)d_in[7];
  const float* dec_Wih = (const float*)d_in[8];
  const float* dec_Whh = (const float*)d_in[9];
  const float* dec_bih = (const float*)d_in[10];
  const float* dec_bhh = (const float*)d_in[11];
  const float* fc_W    = (const float*)d_in[12];
  const float* fc_b    = (const float*)d_in[13];
  float* outp = (float*)d_out;

  // ---- workspace layout (floats), ~32 MB ----
  float* ws = (float*)d_ws;
  const size_t PART = (size_t)KSPLIT * Bb * H3;   // 1572864 floats
  float* pgh0    = ws;                    // gh parts layer0 / decoder parts0
  float* pgi1    = pgh0 + PART;           // gi parts layer1 / decoder parts1
  float* pgh1    = pgi1 + PART;           // gh parts layer1
  float* h_state = pgh1 + PART;           // 2*B*H
  int*   tok     = (int*)(h_state + 2 * Bb * Hh); // 64 ints
  float* gi_ch   = (float*)(tok + 64);    // CH*B*3H

  const size_t Wl = (size_t)H3 * Hh;      // per-layer weight stride
  float* h0 = h_state;
  float* h1 = h_state + Bb * Hh;

  // ---- inits ----
  zero_f32<<<(2 * Bb * Hh + 255) / 256, 256, 0, stream>>>(h_state, 2 * Bb * Hh);
  zero_first<<<(Bb * Vv + 255) / 256, 256, 0, stream>>>(outp);
  tok_init<<<1, 64, 0, stream>>>(tok, trg);

  // ---- encoder: 1-step pipeline skew between the two layers ----
  // macro-step t: layer0 processes timestep t (t<S), layer1 processes t-1 (t>=1)
  for (int t = 0; t <= Ss; ++t) {
    const int has0 = (t < Ss) ? 1 : 0;
    const int has1 = (t >= 1) ? 1 : 0;

    if (has0 && (t & (CH - 1)) == 0) {
      // refill gi0 chunk for timesteps [t, t+CH)
      big_gemm_gather<<<dim3(CH, 48), 256, 0, stream>>>(emb, src, enc_Wih,
                                                        gi_ch, t * Bb);
    }

    const int slot = t & (CH - 1);
    const int ntasks = (has0 ? 384 : 0) + (has1 ? 768 : 0);
    fat_enc<<<ntasks, 256, 0, stream>>>(h0, h1, enc_Whh, enc_Wih + Wl,
                                        enc_Whh + Wl, pgh0, pgi1, pgh1, has0);
    gates2<<<512, 256, 0, stream>>>(gi_ch + (size_t)slot * (64 * H3),
                                    pgh0, enc_bih, enc_bhh, h0,
                                    pgi1, pgh1, enc_bih + H3, enc_bhh + H3, h1,
                                    src_len, t, has0, has1);
  }

  // ---- decoder (verbatim proven schedule) ----
  for (int t = 1; t < Tt; ++t) {
    small_gemm<true><<<dim3(48, KSPLIT, 2), 256, 0, stream>>>(
        nullptr, emb, tok, dec_Wih, pgh0, h0, dec_Whh, pgi1);
    gru_gates<<<256, 256, 0, stream>>>(pgh0, KSPLIT, pgi1, KSPLIT,
                                       dec_bih, dec_bhh, h0, nullptr, nullptr, 0, 0);
    small_gemm<false><<<dim3(48, KSPLIT, 2), 256, 0, stream>>>(
        h0, nullptr, nullptr, dec_Wih + Wl, pgh0, h1, dec_Whh + Wl, pgi1);
    gru_gates<<<256, 256, 0, stream>>>(pgh0, KSPLIT, pgi1, KSPLIT,
                                       dec_bih + H3, dec_bhh + H3, h1, nullptr, nullptr, 0, 0);
    fc_gemm<<<dim3(Vv / 64), 256, 0, stream>>>(h1, fc_W, fc_b, outp, t);
    argmax_k<<<64, 256, 0, stream>>>(outp, t, tok);
  }
}